// Round 1
// baseline (636.147 us; speedup 1.0000x reference)
//
#include <hip/hip_runtime.h>

// Batched Hungarian matcher — exact LSA, scipy-TRAJECTORY-exact.
//
// R7: R6 (row-reduction duals + greedy claim + JV cleanup) produced a
// valid optimal matching but NOT scipy's matching when the optimum is
// non-unique (pre-timing absmax 76 vs thr 81.92; post-timing 548 -> fail).
// Relying on optimum uniqueness over 524k f32 cost entries is unsound.
// This version replicates scipy's _lsa trajectory EXACTLY:
//   - duals start u = v = 0 (no warm start),
//   - rows processed in order 0..127, one shortest-augmenting-path search
//     each, with scipy's exact f64 evaluation order
//         r = ((min_val + cost_f32) - u[i]) - v[j]
//     strictly-better path updates, and lowest-index argmin tie-break.
// => output indices are bit-identical to scipy for ANY tie structure.
// Perf: ~1000 Dijkstra pops/batch (prior-session estimate). New vs R2:
// v[j] is cached in registers per search (v only changes between
// searches), removing 8 LDS b64 reads per pop.

#define Bb 32
#define Nn 4096
#define Mm 128
#define Tt 512
#define Kk (Nn / Tt)   // 8 columns per thread
#define TSH 9          // log2(Tt)
#define NW (Tt / 64)   // 8 waves
#define RECMAX 160

__global__ __launch_bounds__(Tt, 1)
void hungarian_kernel(const float* __restrict__ predict_scores,
                      const float* __restrict__ predict_points,
                      const int*   __restrict__ scores,
                      const float* __restrict__ points,
                      int* __restrict__ out)
{
    __shared__ double vvl[Nn];           // column duals v (exact f64)
    __shared__ short  path_lds[Nn];      // predecessor row per column
    __shared__ short  row4col[Nn];       // matched row per column (-1 free)
    __shared__ double uu[Mm];            // row duals u
    __shared__ short  col4row[Mm];       // matched column per row (-1 free)
    __shared__ double srow_val[Mm];      // shortest[col4row[i]] at scan time
    __shared__ unsigned char SRr[Mm];    // scanned-row flags
    __shared__ float  tx0[Mm], tx1[Mm];
    __shared__ int    tch[Mm];
    __shared__ short  scol[RECMAX];      // popped (SC) columns this search
    __shared__ double sval[RECMAX];      // their pop values
    __shared__ int    nsc_lds;
    __shared__ double wminb[2][NW];      // parity-buffered wave minima
    __shared__ int    wjminb[2][NW];

    const int b   = blockIdx.x;
    const int tid = threadIdx.x;
    const double INFD = __builtin_inf();

    // ---- per-column data -> registers ----
    float negp0[Kk], negp1[Kk], qx0[Kk], qx1[Kk];
    const float* ps = predict_scores + (size_t)b * Nn * 2;
    const float* pp = predict_points + (size_t)b * Nn * 2;
    #pragma unroll
    for (int k = 0; k < Kk; ++k) {
        int j = tid + (k << TSH);
        float2 sc = ((const float2*)ps)[j];
        // bitwise-match jax.nn.softmax: exp(x - max) / sum  (ocml expf both sides)
        float mx = fmaxf(sc.x, sc.y);
        float e0 = expf(sc.x - mx), e1 = expf(sc.y - mx);
        float sm = e0 + e1;
        float n0 = -(e0 / sm), n1 = -(e1 / sm);
        float2 qp = ((const float2*)pp)[j];
        negp0[k] = n0; negp1[k] = n1;
        qx0[k] = qp.x; qx1[k] = qp.y;
        vvl[j] = 0.0;
        row4col[j] = -1;
    }
    if (tid < Mm) {
        col4row[tid] = -1;
        SRr[tid] = 0;
        uu[tid] = 0.0;                    // scipy: duals start at zero
        tx0[tid] = points[(size_t)b * Mm * 2 + 2 * tid];
        tx1[tid] = points[(size_t)b * Mm * 2 + 2 * tid + 1];
        tch[tid] = scores[(size_t)b * Mm + tid];
    }
    __syncthreads();

    // ---- JV: one shortest-augmenting-path search per row, scipy order ----
    for (int cur_row = 0; cur_row < Mm; ++cur_row) {
        double shr[Kk];                   // shortest[] slice (registers)
        double vreg[Kk];                  // v[] slice cached (const per search)
        #pragma unroll
        for (int k = 0; k < Kk; ++k) {
            shr[k]  = INFD;
            vreg[k] = vvl[tid + (k << TSH)];
        }
        unsigned scmask = 0;              // SC flags for my 8 columns
        int    i = cur_row;
        double minv = 0.0;
        int    sink = -1, par = 0, nsc = 0;

        for (;;) {
            // ---- relax row i over all 4096 columns (exact f64, scipy order) ----
            const double ui = uu[i];
            const float  t0 = tx0[i], t1 = tx1[i];
            const int    ch = tch[i];
            double bv = INFD; int bj = 0;
            #pragma unroll
            for (int k = 0; k < Kk; ++k) {
                int j = tid + (k << TSH);
                float pres = (ch == 1) ? negp1[k] : negp0[k];
                float cf = pres + (fabsf(qx0[k] - t0) + fabsf(qx1[k] - t1));
                double r = ((minv + (double)cf) - ui) - vreg[k];
                bool sc = (scmask >> k) & 1u;
                if (!sc && r < shr[k]) { shr[k] = r; path_lds[j] = (short)i; }
                double sj = sc ? INFD : shr[k];
                if (sj < bv) { bv = sj; bj = j; }   // k asc => lowest j on tie
            }
            #pragma unroll
            for (int off = 32; off > 0; off >>= 1) {
                double ov = __shfl_down(bv, off);
                int    oj = __shfl_down(bj, off);
                if (ov < bv || (ov == bv && oj < bj)) { bv = ov; bj = oj; }
            }
            if ((tid & 63) == 0) { wminb[par][tid >> 6] = bv; wjminb[par][tid >> 6] = bj; }
            __syncthreads();
            double best = wminb[par][0]; int bestj = wjminb[par][0];
            #pragma unroll
            for (int w = 1; w < NW; ++w) {
                double ov = wminb[par][w]; int oj = wjminb[par][w];
                if (ov < best || (ov == best && oj < bestj)) { best = ov; bestj = oj; }
            }
            par ^= 1;
            minv = best;
            if ((bestj & (Tt - 1)) == tid) scmask |= (1u << (bestj >> TSH));
            int r4 = row4col[bestj];
            if (r4 < 0) {
                if (tid == 0) nsc_lds = nsc;
                sink = bestj;
                break;                             // uniform exit
            }
            if (tid == 0) {
                SRr[r4] = 1; srow_val[r4] = best;
                scol[nsc] = bestj; sval[nsc] = best; ++nsc;
            }
            i = r4;
        }
        __syncthreads();                           // publish nsc/SRr/records

        // ---- dual updates (scipy-exact op order) + augment ----
        const double minvF = minv;
        if (tid < Mm) {
            if (tid == cur_row)   uu[tid] += minvF;
            else if (SRr[tid])    uu[tid] += minvF - srow_val[tid];
            SRr[tid] = 0;
        }
        int S = nsc_lds;
        if (tid < S) {
            int jc = scol[tid];
            vvl[jc] -= (minvF - sval[tid]);
        }
        if (tid == 0) {
            int j = sink;
            for (;;) {
                int i2 = path_lds[j];
                row4col[j] = (short)i2;
                int nxt = col4row[i2];
                col4row[i2] = (short)j;
                j = nxt;
                if (i2 == cur_row) break;
            }
        }
        __syncthreads();
    }

    // ---- emit (batch, src sorted ascending, tgt) ----
    if (tid < Mm) {
        int myj = col4row[tid];
        int rank = 0;
        #pragma unroll 4
        for (int t = 0; t < Mm; ++t) rank += (col4row[t] < myj) ? 1 : 0;
        out[b * Mm + tid] = b;                  // batch_idx
        out[Bb * Mm + b * Mm + rank] = myj;     // src_idx (sorted)
        out[2 * Bb * Mm + b * Mm + rank] = tid; // tgt_idx
    }
}

extern "C" void kernel_launch(void* const* d_in, const int* in_sizes, int n_in,
                              void* d_out, int out_size, void* d_ws, size_t ws_size,
                              hipStream_t stream) {
    (void)in_sizes; (void)n_in; (void)d_ws; (void)ws_size; (void)out_size;
    const float* predict_scores = (const float*)d_in[0];
    const float* predict_points = (const float*)d_in[1];
    const int*   scores         = (const int*)d_in[2];
    const float* points         = (const float*)d_in[3];
    int* out = (int*)d_out;
    hipLaunchKernelGGL(hungarian_kernel, dim3(Bb), dim3(Tt), 0, stream,
                       predict_scores, predict_points, scores, points, out);
}